// Round 12
// baseline (89.138 us; speedup 1.0000x reference)
//
#include <hip/hip_runtime.h>
#include <stdint.h>
#include <stddef.h>

#define VV 3
#define NN 4096
#define DD 512
#define CC 10

typedef unsigned short bf16_t;
typedef __attribute__((ext_vector_type(8))) short bf16x8;
typedef __attribute__((ext_vector_type(4))) float f32x4;

#define MFMA16 __builtin_amdgcn_mfma_f32_16x16x32_bf16

__device__ __forceinline__ float bf2f(unsigned u) {
  union { unsigned u; float f; } c; c.u = u << 16; return c.f;
}
__device__ __forceinline__ bf16_t f2bf(float f) {
  union { float f; unsigned u; } c; c.f = f;
  unsigned r = (c.u + 0x7FFFu + ((c.u >> 16) & 1u)) >> 16;
  return (bf16_t)r;
}
__device__ __forceinline__ float splus(float x) {
  float ax = fabsf(x);
  return fmaxf(x, 0.0f) + log1pf(expf(-ax));
}

// ---------------- K1: fused prep (R10-proven) -------------------------------
// blocks [0,3072):      A -> bitmask (ballot-native layout) + dinv
// blocks [3072,3457):   Wc_t = (W1@W2)^T bf16 (padded 16 rows), bp = b1@W2
// blocks [3457,3463):   Wm_t = W_mlp^T bf16 (padded 16 rows)
// mask word layout: word wi of a row, bit b <-> column (wi>>2)*256 + 4b + (wi&3)
// Plain cacheable loads on A (L3 retains ~40% across replays); coalesced
// row-major mask writes. Symmetric tile scan regressed (R11: scattered writes).
__global__ __launch_bounds__(256) void k_prep(const float* __restrict__ A,
    const float* __restrict__ W1, const float* __restrict__ b1,
    const float* __restrict__ W2, const float* __restrict__ W_mlp,
    unsigned long long* __restrict__ mask, float* __restrict__ dinv,
    bf16_t* __restrict__ Wc_t, float* __restrict__ bp, bf16_t* __restrict__ Wm_t)
{
  int t = threadIdx.x;
  int w = t >> 6, lane = t & 63;
  if (blockIdx.x < VV * NN / 4) {
    size_t row = (size_t)blockIdx.x * 4 + w;     // one row per wave
    const f32x4* r4 = (const f32x4*)(A + row * NN);
    unsigned long long myw = 0ull;
#pragma unroll 8
    for (int it = 0; it < 16; ++it) {
      f32x4 x = r4[it * 64 + lane];
      unsigned long long q0 = __ballot(x[0] != 0.0f);
      unsigned long long q1 = __ballot(x[1] != 0.0f);
      unsigned long long q2 = __ballot(x[2] != 0.0f);
      unsigned long long q3 = __ballot(x[3] != 0.0f);
      if ((lane >> 2) == it) {
        int k = lane & 3;
        myw = (k == 0) ? q0 : (k == 1) ? q1 : (k == 2) ? q2 : q3;
      }
    }
    mask[row * 64 + lane] = myw;
    int pc = __popcll(myw);
#pragma unroll
    for (int s = 32; s; s >>= 1) pc += __shfl_xor(pc, s);
    if (lane == 0) dinv[row] = 1.0f / sqrtf((float)(pc + 1)); // deg = popc+1 (+I)
  } else if (blockIdx.x < VV * NN / 4 + 385) {
    int wid = (blockIdx.x - VV * NN / 4) * 4 + w;
    if (wid >= VV * 513) return;
    int v = wid / 513, dd2 = wid % 513;
    const float* w2 = W2 + (size_t)v * DD * CC;
    const float* src = (dd2 < DD) ? (W1 + ((size_t)v * DD + dd2) * DD) : (b1 + (size_t)v * DD);
    float acc[CC];
#pragma unroll
    for (int c = 0; c < CC; ++c) acc[c] = 0.f;
    for (int it = 0; it < 8; ++it) {
      float wv = src[it * 64 + lane];
      const float* w2r = w2 + (size_t)(it * 64 + lane) * CC;
#pragma unroll
      for (int c = 0; c < CC; ++c) acc[c] += wv * w2r[c];
    }
#pragma unroll
    for (int c = 0; c < CC; ++c) {
#pragma unroll
      for (int s = 32; s; s >>= 1) acc[c] += __shfl_xor(acc[c], s);
    }
    if (lane == 0) {
      if (dd2 < DD) {
#pragma unroll
        for (int c = 0; c < CC; ++c) Wc_t[((size_t)v * 16 + c) * DD + dd2] = f2bf(acc[c]);
#pragma unroll
        for (int c = CC; c < 16; ++c) Wc_t[((size_t)v * 16 + c) * DD + dd2] = 0;
      } else {
#pragma unroll
        for (int c = 0; c < CC; ++c) bp[v * CC + c] = acc[c];
      }
    }
  } else {
    int idx = (blockIdx.x - (VV * NN / 4 + 385)) * 256 + t;
    if (idx >= VV * DD) return;
    int v = idx / DD, d = idx % DD;
#pragma unroll
    for (int c = 0; c < CC; ++c)
      Wm_t[((size_t)v * 16 + c) * DD + d] = f2bf(W_mlp[((size_t)v * DD + d) * CC + c]);
#pragma unroll
    for (int c = CC; c < 16; ++c) Wm_t[((size_t)v * 16 + c) * DD + d] = 0;
  }
}

// ---------------- K2: Ps1p[v][c/2][j] = packed bf16 pair of dinv_j*(X·Wc) ---
//                      E[v,j,c] = consensus + softplus(X·Wm + bm)
__global__ __launch_bounds__(256) void k_zs(
    const float* __restrict__ X,
    const bf16_t* __restrict__ Wc_t, const bf16_t* __restrict__ Wm_t,
    const float* __restrict__ b_mlp, const float* __restrict__ consensus,
    const float* __restrict__ dinv,
    unsigned* __restrict__ Ps1p, float* __restrict__ E)
{
  __shared__ bf16_t Bc[16 * 520];
  __shared__ bf16_t Bm[16 * 520];
  int v = blockIdx.y;
  int t = threadIdx.x;
  {
    int r = t & 15, ch = t >> 4;
    const bf16_t* sc = Wc_t + (size_t)v * 16 * DD + (size_t)r * DD + ch * 32;
    const bf16_t* sm = Wm_t + (size_t)v * 16 * DD + (size_t)r * DD + ch * 32;
    bf16_t* dc = &Bc[r * 520 + ch * 32];
    bf16_t* dm = &Bm[r * 520 + ch * 32];
#pragma unroll
    for (int q = 0; q < 4; ++q) {
      *(bf16x8*)(dc + q * 8) = *(const bf16x8*)(sc + q * 8);
      *(bf16x8*)(dm + q * 8) = *(const bf16x8*)(sm + q * 8);
    }
  }
  __syncthreads();
  int w = t >> 6, lane = t & 63;
  int fl = lane & 15, fh = lane >> 4;
  int r0 = blockIdx.x * 64 + w * 16;
  const float* Xrow = X + ((size_t)v * NN + r0 + fl) * DD;
  f32x4 aP = {0.f, 0.f, 0.f, 0.f}, aM = {0.f, 0.f, 0.f, 0.f};
#pragma unroll
  for (int k = 0; k < 16; ++k) {
    float4 x0 = *(const float4*)(Xrow + k * 32 + fh * 8);
    float4 x1 = *(const float4*)(Xrow + k * 32 + fh * 8 + 4);
    bf16x8 a = { (short)f2bf(x0.x), (short)f2bf(x0.y), (short)f2bf(x0.z), (short)f2bf(x0.w),
                 (short)f2bf(x1.x), (short)f2bf(x1.y), (short)f2bf(x1.z), (short)f2bf(x1.w) };
    bf16x8 b1v = *(const bf16x8*)(&Bc[fl * 520 + k * 32 + fh * 8]);
    aP = MFMA16(a, b1v, aP, 0, 0, 0);
    bf16x8 b2v = *(const bf16x8*)(&Bm[fl * 520 + k * 32 + fh * 8]);
    aM = MFMA16(a, b2v, aM, 0, 0, 0);
  }
  float bmv = (fl < CC) ? b_mlp[v * CC + fl] : 0.f;
#pragma unroll
  for (int g = 0; g < 4; ++g) {
    int j = r0 + fh * 4 + g;
    float dj = dinv[(size_t)v * NN + j];
    float val = aP[g] * dj;
    float part = __shfl_xor(val, 1);            // partner channel fl^1, same j
    if (((fl & 1) == 0) && fl < CC) {
      unsigned pw = (unsigned)f2bf(val) | ((unsigned)f2bf(part) << 16);
      Ps1p[((size_t)v * 5 + (fl >> 1)) * NN + j] = pw;
    }
    if (fl < CC) {
      size_t ad = ((size_t)v * NN + j) * CC + fl;
      E[ad] = consensus[ad] + splus(aM[g] + bmv);
    }
  }
}

// ---- shared gather core: 8-lane group per row, ballot-native bit decode ----
#define SPMM_PROLOG(SRC_) \
  __shared__ unsigned PsL[5 * NN];  /* 80 KB */ \
  int v = blockIdx.y; \
  int t = threadIdx.x; \
  { \
    const uint4* src_ = (const uint4*)((SRC_) + (size_t)v * 5 * NN); \
    uint4* dst_ = (uint4*)PsL; \
    _Pragma("unroll") \
    for (int q = 0; q < 20; ++q) dst_[q * 256 + t] = src_[q * 256 + t]; \
  } \
  __syncthreads(); \
  int w = t >> 6, g = (t >> 3) & 7, s = t & 7; \
  int i = blockIdx.x * 32 + w * 8 + g; \
  const unsigned long long* mrow = mask + ((size_t)v * NN + i) * 64; \
  float acc[CC]; \
  _Pragma("unroll") \
  for (int c = 0; c < CC; ++c) acc[c] = 0.f; \
  _Pragma("unroll") \
  for (int it = 0; it < 8; ++it) { \
    int wi = it * 8 + s; \
    unsigned long long bits = mrow[wi]; \
    int jb = (wi >> 2) * 256 + (wi & 3); \
    while (bits) { \
      int b = __builtin_ctzll(bits); \
      bits &= bits - 1; \
      int j = jb + (b << 2); \
      _Pragma("unroll") \
      for (int c2 = 0; c2 < 5; ++c2) { \
        unsigned pw = PsL[c2 * NN + j]; \
        acc[2 * c2]     += bf2f(pw & 0xFFFFu); \
        acc[2 * c2 + 1] += bf2f(pw >> 16); \
      } \
    } \
  } \
  _Pragma("unroll") \
  for (int c = 0; c < CC; ++c) { \
    acc[c] += __shfl_xor(acc[c], 1); \
    acc[c] += __shfl_xor(acc[c], 2); \
    acc[c] += __shfl_xor(acc[c], 4); \
  }

// ---------------- K3: P2p[c/2][i] = pack(di*(di*(Ahat@Ps1)[i,c] + bp_c)) ----
__global__ __launch_bounds__(256) void k_spmm1(
    const unsigned long long* __restrict__ mask, const unsigned* __restrict__ Ps1p,
    const float* __restrict__ bp, const float* __restrict__ dinv,
    unsigned* __restrict__ P2p)
{
  SPMM_PROLOG(Ps1p)
  if (s == 0) {
    float di = dinv[(size_t)v * NN + i];
#pragma unroll
    for (int c2 = 0; c2 < 5; ++c2) {             // + self (the +I)
      unsigned pw = PsL[c2 * NN + i];
      acc[2 * c2]     += bf2f(pw & 0xFFFFu);
      acc[2 * c2 + 1] += bf2f(pw >> 16);
    }
#pragma unroll
    for (int c2 = 0; c2 < 5; ++c2) {
      float lo = di * (di * acc[2 * c2]     + bp[v * CC + 2 * c2]);
      float hi = di * (di * acc[2 * c2 + 1] + bp[v * CC + 2 * c2 + 1]);
      P2p[((size_t)v * 5 + c2) * NN + i] = (unsigned)f2bf(lo) | ((unsigned)f2bf(hi) << 16);
    }
  }
}

// ---------------- K4: E += softplus(di*(Ahat@P2) + b2) ----------------------
__global__ __launch_bounds__(256) void k_spmm2(
    const unsigned long long* __restrict__ mask, const unsigned* __restrict__ P2p,
    const float* __restrict__ b2, const float* __restrict__ dinv,
    float* __restrict__ E)
{
  SPMM_PROLOG(P2p)
  if (s == 0) {
    float di = dinv[(size_t)v * NN + i];
#pragma unroll
    for (int c2 = 0; c2 < 5; ++c2) {             // + self (the +I)
      unsigned pw = PsL[c2 * NN + i];
      acc[2 * c2]     += bf2f(pw & 0xFFFFu);
      acc[2 * c2 + 1] += bf2f(pw >> 16);
    }
    float* Eo = E + ((size_t)v * NN + i) * CC;
#pragma unroll
    for (int c = 0; c < CC; ++c)
      Eo[c] = Eo[c] + splus(di * acc[c] + b2[v * CC + c]);
  }
}

// ---------------- K5: fused sim + coef + agg (160 blocks, redundant sim) ----
// Each block reduces the full 480 KB E (L2-resident) itself (~2us aggregate):
// removes the k_sim kernel + its launch gap + the partial round-trip. [R11-proven]
__global__ __launch_bounds__(256) void k_aggc(const float* __restrict__ E,
                                              float* __restrict__ agg)
{
  __shared__ float sm[3][256];
  int t = threadIdx.x;
  float d01 = 0, d02 = 0, d12 = 0;
  for (int q = 0; q < 16; ++q) {
    int n = q * 256 + t;
    float e0[CC], e1[CC], e2[CC];
#pragma unroll
    for (int c = 0; c < CC; ++c) {
      e0[c] = E[(size_t)(0 * NN + n) * CC + c];
      e1[c] = E[(size_t)(1 * NN + n) * CC + c];
      e2[c] = E[(size_t)(2 * NN + n) * CC + c];
    }
    float n0 = 0, n1 = 0, n2 = 0, p01 = 0, p02 = 0, p12 = 0;
#pragma unroll
    for (int c = 0; c < CC; ++c) { n0 += e0[c]*e0[c]; n1 += e1[c]*e1[c]; n2 += e2[c]*e2[c]; }
    float i0 = 1.0f / fmaxf(sqrtf(n0), 1e-8f);
    float i1 = 1.0f / fmaxf(sqrtf(n1), 1e-8f);
    float i2 = 1.0f / fmaxf(sqrtf(n2), 1e-8f);
#pragma unroll
    for (int c = 0; c < CC; ++c) { p01 += e0[c]*e1[c]; p02 += e0[c]*e2[c]; p12 += e1[c]*e2[c]; }
    d01 += p01 * i0 * i1; d02 += p02 * i0 * i2; d12 += p12 * i1 * i2;
  }
  sm[0][t] = d01; sm[1][t] = d02; sm[2][t] = d12;
  __syncthreads();
  for (int s = 128; s; s >>= 1) {
    if (t < s) { sm[0][t] += sm[0][t+s]; sm[1][t] += sm[1][t+s]; sm[2][t] += sm[2][t+s]; }
    __syncthreads();
  }
  float S01 = sm[0][0] / (float)NN, S02 = sm[1][0] / (float)NN, S12 = sm[2][0] / (float)NN;
  float mx = fmaxf(S01, fmaxf(S02, S12));
  float thr = 0.7f * mx;
  float w01 = (S01 > thr) ? S01 : 0.f;
  float w02 = (S02 > thr) ? S02 : 0.f;
  float m0 = fmaxf(w01, w02);
  float e01 = expf(w01 - m0), e02 = expf(w02 - m0);
  float s0 = e01 + e02;
  float p01 = e01 / s0, p02 = e02 / s0;
  float p12 = 1.0f;                      // row-1 softmax over its single edge
  float c0 = (p01 + p02) / 6.0f;
  float c1 = (p12 + p01) / 6.0f;
  float c2 = (p02 + p12) / 6.0f;
  int idx = blockIdx.x * 256 + t;
  agg[idx] = c0 * E[idx] + c1 * E[NN * CC + idx] + c2 * E[2 * NN * CC + idx];
}

// ---------------------------------------------------------------------------
extern "C" void kernel_launch(void* const* d_in, const int* in_sizes, int n_in,
                              void* d_out, int out_size, void* d_ws, size_t ws_size,
                              hipStream_t stream)
{
  (void)in_sizes; (void)n_in; (void)out_size;
  const float* X         = (const float*)d_in[0];
  const float* A         = (const float*)d_in[1];
  const float* consensus = (const float*)d_in[2];
  const float* W_mlp     = (const float*)d_in[3];
  const float* b_mlp     = (const float*)d_in[4];
  const float* W1        = (const float*)d_in[5];
  const float* b1        = (const float*)d_in[6];
  const float* W2        = (const float*)d_in[7];
  const float* b2        = (const float*)d_in[8];
  float* Eout = (float*)d_out;
  float* aggout = Eout + (size_t)VV * NN * CC;

  char* ws = (char*)d_ws;
  size_t off = 0;
  auto alloc = [&](size_t b) { char* p = ws + off; off += (b + 255) & ~(size_t)255; return p; };
  unsigned long long* mask = (unsigned long long*)alloc((size_t)VV * NN * 64 * 8);
  bf16_t* Wc_t  = (bf16_t*)alloc((size_t)VV * 16 * DD * 2);
  bf16_t* Wm_t  = (bf16_t*)alloc((size_t)VV * 16 * DD * 2);
  float*  bp    = (float*) alloc((size_t)VV * CC * 4);
  float*  dinv  = (float*) alloc((size_t)VV * NN * 4);
  unsigned* Ps1p = (unsigned*)alloc((size_t)VV * 5 * NN * 4);
  unsigned* P2p  = (unsigned*)alloc((size_t)VV * 5 * NN * 4);
  if (off > ws_size) return;

  k_prep <<<VV * NN / 4 + 385 + 6, 256, 0, stream>>>(A, W1, b1, W2, W_mlp,
                                                     mask, dinv, Wc_t, bp, Wm_t);
  k_zs   <<<dim3(NN / 64, VV), 256, 0, stream>>>(X, Wc_t, Wm_t, b_mlp, consensus,
                                                 dinv, Ps1p, Eout);
  k_spmm1<<<dim3(NN / 32, VV), 256, 0, stream>>>(mask, Ps1p, bp, dinv, P2p);
  k_spmm2<<<dim3(NN / 32, VV), 256, 0, stream>>>(mask, P2p, b2, dinv, Eout);
  k_aggc <<<160, 256, 0, stream>>>(Eout, aggout);
}

// Round 13
// 80.130 us; speedup vs baseline: 1.1124x; 1.1124x over previous
//
#include <hip/hip_runtime.h>
#include <stdint.h>
#include <stddef.h>

#define VV 3
#define NN 4096
#define DD 512
#define CC 10

typedef unsigned short bf16_t;
typedef __attribute__((ext_vector_type(8))) short bf16x8;
typedef __attribute__((ext_vector_type(4))) float f32x4;

#define MFMA16 __builtin_amdgcn_mfma_f32_16x16x32_bf16

__device__ __forceinline__ float bf2f(unsigned u) {
  union { unsigned u; float f; } c; c.u = u << 16; return c.f;
}
__device__ __forceinline__ bf16_t f2bf(float f) {
  union { float f; unsigned u; } c; c.f = f;
  unsigned r = (c.u + 0x7FFFu + ((c.u >> 16) & 1u)) >> 16;
  return (bf16_t)r;
}
__device__ __forceinline__ float splus(float x) {
  float ax = fabsf(x);
  return fmaxf(x, 0.0f) + log1pf(expf(-ax));
}

// ---------------- K1: fused prep (R10-proven) -------------------------------
// blocks [0,3072):      A -> bitmask (ballot-native layout) + dinv
// blocks [3072,3457):   Wc_t = (W1@W2)^T bf16 (padded 16 rows), bp = b1@W2
// blocks [3457,3463):   Wm_t = W_mlp^T bf16 (padded 16 rows)
// mask word layout: word wi of a row, bit b <-> column (wi>>2)*256 + 4b + (wi&3)
__global__ __launch_bounds__(256) void k_prep(const float* __restrict__ A,
    const float* __restrict__ W1, const float* __restrict__ b1,
    const float* __restrict__ W2, const float* __restrict__ W_mlp,
    unsigned long long* __restrict__ mask, float* __restrict__ dinv,
    bf16_t* __restrict__ Wc_t, float* __restrict__ bp, bf16_t* __restrict__ Wm_t)
{
  int t = threadIdx.x;
  int w = t >> 6, lane = t & 63;
  if (blockIdx.x < VV * NN / 4) {
    size_t row = (size_t)blockIdx.x * 4 + w;     // one row per wave
    const f32x4* r4 = (const f32x4*)(A + row * NN);
    unsigned long long myw = 0ull;
#pragma unroll 8
    for (int it = 0; it < 16; ++it) {
      f32x4 x = r4[it * 64 + lane];
      unsigned long long q0 = __ballot(x[0] != 0.0f);
      unsigned long long q1 = __ballot(x[1] != 0.0f);
      unsigned long long q2 = __ballot(x[2] != 0.0f);
      unsigned long long q3 = __ballot(x[3] != 0.0f);
      if ((lane >> 2) == it) {
        int k = lane & 3;
        myw = (k == 0) ? q0 : (k == 1) ? q1 : (k == 2) ? q2 : q3;
      }
    }
    mask[row * 64 + lane] = myw;
    int pc = __popcll(myw);
#pragma unroll
    for (int s = 32; s; s >>= 1) pc += __shfl_xor(pc, s);
    if (lane == 0) dinv[row] = 1.0f / sqrtf((float)(pc + 1)); // deg = popc+1 (+I)
  } else if (blockIdx.x < VV * NN / 4 + 385) {
    int wid = (blockIdx.x - VV * NN / 4) * 4 + w;
    if (wid >= VV * 513) return;
    int v = wid / 513, dd2 = wid % 513;
    const float* w2 = W2 + (size_t)v * DD * CC;
    const float* src = (dd2 < DD) ? (W1 + ((size_t)v * DD + dd2) * DD) : (b1 + (size_t)v * DD);
    float acc[CC];
#pragma unroll
    for (int c = 0; c < CC; ++c) acc[c] = 0.f;
    for (int it = 0; it < 8; ++it) {
      float wv = src[it * 64 + lane];
      const float* w2r = w2 + (size_t)(it * 64 + lane) * CC;
#pragma unroll
      for (int c = 0; c < CC; ++c) acc[c] += wv * w2r[c];
    }
#pragma unroll
    for (int c = 0; c < CC; ++c) {
#pragma unroll
      for (int s = 32; s; s >>= 1) acc[c] += __shfl_xor(acc[c], s);
    }
    if (lane == 0) {
      if (dd2 < DD) {
#pragma unroll
        for (int c = 0; c < CC; ++c) Wc_t[((size_t)v * 16 + c) * DD + dd2] = f2bf(acc[c]);
#pragma unroll
        for (int c = CC; c < 16; ++c) Wc_t[((size_t)v * 16 + c) * DD + dd2] = 0;
      } else {
#pragma unroll
        for (int c = 0; c < CC; ++c) bp[v * CC + c] = acc[c];
      }
    }
  } else {
    int idx = (blockIdx.x - (VV * NN / 4 + 385)) * 256 + t;
    if (idx >= VV * DD) return;
    int v = idx / DD, d = idx % DD;
#pragma unroll
    for (int c = 0; c < CC; ++c)
      Wm_t[((size_t)v * 16 + c) * DD + d] = f2bf(W_mlp[((size_t)v * DD + d) * CC + c]);
#pragma unroll
    for (int c = CC; c < 16; ++c) Wm_t[((size_t)v * 16 + c) * DD + d] = 0;
  }
}

// ---------------- K2: Ps1p[v][c/2][j] = packed bf16 pair of dinv_j*(X·Wc) ---
//                      E[v,j,c] = consensus + softplus(X·Wm + bm)
__global__ __launch_bounds__(256) void k_zs(
    const float* __restrict__ X,
    const bf16_t* __restrict__ Wc_t, const bf16_t* __restrict__ Wm_t,
    const float* __restrict__ b_mlp, const float* __restrict__ consensus,
    const float* __restrict__ dinv,
    unsigned* __restrict__ Ps1p, float* __restrict__ E)
{
  __shared__ bf16_t Bc[16 * 520];
  __shared__ bf16_t Bm[16 * 520];
  int v = blockIdx.y;
  int t = threadIdx.x;
  {
    int r = t & 15, ch = t >> 4;
    const bf16_t* sc = Wc_t + (size_t)v * 16 * DD + (size_t)r * DD + ch * 32;
    const bf16_t* sm = Wm_t + (size_t)v * 16 * DD + (size_t)r * DD + ch * 32;
    bf16_t* dc = &Bc[r * 520 + ch * 32];
    bf16_t* dm = &Bm[r * 520 + ch * 32];
#pragma unroll
    for (int q = 0; q < 4; ++q) {
      *(bf16x8*)(dc + q * 8) = *(const bf16x8*)(sc + q * 8);
      *(bf16x8*)(dm + q * 8) = *(const bf16x8*)(sm + q * 8);
    }
  }
  __syncthreads();
  int w = t >> 6, lane = t & 63;
  int fl = lane & 15, fh = lane >> 4;
  int r0 = blockIdx.x * 64 + w * 16;
  const float* Xrow = X + ((size_t)v * NN + r0 + fl) * DD;
  f32x4 aP = {0.f, 0.f, 0.f, 0.f}, aM = {0.f, 0.f, 0.f, 0.f};
#pragma unroll
  for (int k = 0; k < 16; ++k) {
    float4 x0 = *(const float4*)(Xrow + k * 32 + fh * 8);
    float4 x1 = *(const float4*)(Xrow + k * 32 + fh * 8 + 4);
    bf16x8 a = { (short)f2bf(x0.x), (short)f2bf(x0.y), (short)f2bf(x0.z), (short)f2bf(x0.w),
                 (short)f2bf(x1.x), (short)f2bf(x1.y), (short)f2bf(x1.z), (short)f2bf(x1.w) };
    bf16x8 b1v = *(const bf16x8*)(&Bc[fl * 520 + k * 32 + fh * 8]);
    aP = MFMA16(a, b1v, aP, 0, 0, 0);
    bf16x8 b2v = *(const bf16x8*)(&Bm[fl * 520 + k * 32 + fh * 8]);
    aM = MFMA16(a, b2v, aM, 0, 0, 0);
  }
  float bmv = (fl < CC) ? b_mlp[v * CC + fl] : 0.f;
#pragma unroll
  for (int g = 0; g < 4; ++g) {
    int j = r0 + fh * 4 + g;
    float dj = dinv[(size_t)v * NN + j];
    float val = aP[g] * dj;
    float part = __shfl_xor(val, 1);            // partner channel fl^1, same j
    if (((fl & 1) == 0) && fl < CC) {
      unsigned pw = (unsigned)f2bf(val) | ((unsigned)f2bf(part) << 16);
      Ps1p[((size_t)v * 5 + (fl >> 1)) * NN + j] = pw;
    }
    if (fl < CC) {
      size_t ad = ((size_t)v * NN + j) * CC + fl;
      E[ad] = consensus[ad] + splus(aM[g] + bmv);
    }
  }
}

// ---- shared gather core: 8-lane group per row, ballot-native bit decode ----
#define SPMM_PROLOG(SRC_) \
  __shared__ unsigned PsL[5 * NN];  /* 80 KB */ \
  int v = blockIdx.y; \
  int t = threadIdx.x; \
  { \
    const uint4* src_ = (const uint4*)((SRC_) + (size_t)v * 5 * NN); \
    uint4* dst_ = (uint4*)PsL; \
    _Pragma("unroll") \
    for (int q = 0; q < 20; ++q) dst_[q * 256 + t] = src_[q * 256 + t]; \
  } \
  __syncthreads(); \
  int w = t >> 6, g = (t >> 3) & 7, s = t & 7; \
  int i = blockIdx.x * 32 + w * 8 + g; \
  const unsigned long long* mrow = mask + ((size_t)v * NN + i) * 64; \
  float acc[CC]; \
  _Pragma("unroll") \
  for (int c = 0; c < CC; ++c) acc[c] = 0.f; \
  _Pragma("unroll") \
  for (int it = 0; it < 8; ++it) { \
    int wi = it * 8 + s; \
    unsigned long long bits = mrow[wi]; \
    int jb = (wi >> 2) * 256 + (wi & 3); \
    while (bits) { \
      int b = __builtin_ctzll(bits); \
      bits &= bits - 1; \
      int j = jb + (b << 2); \
      _Pragma("unroll") \
      for (int c2 = 0; c2 < 5; ++c2) { \
        unsigned pw = PsL[c2 * NN + j]; \
        acc[2 * c2]     += bf2f(pw & 0xFFFFu); \
        acc[2 * c2 + 1] += bf2f(pw >> 16); \
      } \
    } \
  } \
  _Pragma("unroll") \
  for (int c = 0; c < CC; ++c) { \
    acc[c] += __shfl_xor(acc[c], 1); \
    acc[c] += __shfl_xor(acc[c], 2); \
    acc[c] += __shfl_xor(acc[c], 4); \
  }

// ---------------- K3: P2p[c/2][i] = pack(di*(di*(Ahat@Ps1)[i,c] + bp_c)) ----
__global__ __launch_bounds__(256) void k_spmm1(
    const unsigned long long* __restrict__ mask, const unsigned* __restrict__ Ps1p,
    const float* __restrict__ bp, const float* __restrict__ dinv,
    unsigned* __restrict__ P2p)
{
  SPMM_PROLOG(Ps1p)
  if (s == 0) {
    float di = dinv[(size_t)v * NN + i];
#pragma unroll
    for (int c2 = 0; c2 < 5; ++c2) {             // + self (the +I)
      unsigned pw = PsL[c2 * NN + i];
      acc[2 * c2]     += bf2f(pw & 0xFFFFu);
      acc[2 * c2 + 1] += bf2f(pw >> 16);
    }
#pragma unroll
    for (int c2 = 0; c2 < 5; ++c2) {
      float lo = di * (di * acc[2 * c2]     + bp[v * CC + 2 * c2]);
      float hi = di * (di * acc[2 * c2 + 1] + bp[v * CC + 2 * c2 + 1]);
      P2p[((size_t)v * 5 + c2) * NN + i] = (unsigned)f2bf(lo) | ((unsigned)f2bf(hi) << 16);
    }
  }
}

// ---------------- K4: E += softplus(di*(Ahat@P2) + b2) ----------------------
__global__ __launch_bounds__(256) void k_spmm2(
    const unsigned long long* __restrict__ mask, const unsigned* __restrict__ P2p,
    const float* __restrict__ b2, const float* __restrict__ dinv,
    float* __restrict__ E)
{
  SPMM_PROLOG(P2p)
  if (s == 0) {
    float di = dinv[(size_t)v * NN + i];
#pragma unroll
    for (int c2 = 0; c2 < 5; ++c2) {             // + self (the +I)
      unsigned pw = PsL[c2 * NN + i];
      acc[2 * c2]     += bf2f(pw & 0xFFFFu);
      acc[2 * c2 + 1] += bf2f(pw >> 16);
    }
    float* Eo = E + ((size_t)v * NN + i) * CC;
#pragma unroll
    for (int c = 0; c < CC; ++c)
      Eo[c] = Eo[c] + splus(di * acc[c] + b2[v * CC + c]);
  }
}

// ---------------- K5: per-block partial sums of pairwise cosine dots --------
// Split tail (16-block sim + 160-block agg) beats fused redundant sim:
// per-XCD L2s are private, so 160 blocks re-reading all of E hits L3 (R12).
__global__ __launch_bounds__(256) void k_sim(const float* __restrict__ E,
                                             float* __restrict__ partial)
{
  __shared__ float sm[3][256];
  int t = threadIdx.x;
  int n = blockIdx.x * 256 + t;
  float e0[CC], e1[CC], e2[CC];
#pragma unroll
  for (int c = 0; c < CC; ++c) {
    e0[c] = E[(size_t)(0 * NN + n) * CC + c];
    e1[c] = E[(size_t)(1 * NN + n) * CC + c];
    e2[c] = E[(size_t)(2 * NN + n) * CC + c];
  }
  float n0 = 0, n1 = 0, n2 = 0, d01 = 0, d02 = 0, d12 = 0;
#pragma unroll
  for (int c = 0; c < CC; ++c) { n0 += e0[c]*e0[c]; n1 += e1[c]*e1[c]; n2 += e2[c]*e2[c]; }
  float i0 = 1.0f / fmaxf(sqrtf(n0), 1e-8f);
  float i1 = 1.0f / fmaxf(sqrtf(n1), 1e-8f);
  float i2 = 1.0f / fmaxf(sqrtf(n2), 1e-8f);
#pragma unroll
  for (int c = 0; c < CC; ++c) { d01 += e0[c]*e1[c]; d02 += e0[c]*e2[c]; d12 += e1[c]*e2[c]; }
  sm[0][t] = d01 * i0 * i1;
  sm[1][t] = d02 * i0 * i2;
  sm[2][t] = d12 * i1 * i2;
  __syncthreads();
  for (int s = 128; s; s >>= 1) {
    if (t < s) { sm[0][t] += sm[0][t+s]; sm[1][t] += sm[1][t+s]; sm[2][t] += sm[2][t+s]; }
    __syncthreads();
  }
  if (t == 0) {
    partial[blockIdx.x * 3 + 0] = sm[0][0];
    partial[blockIdx.x * 3 + 1] = sm[1][0];
    partial[blockIdx.x * 3 + 2] = sm[2][0];
  }
}

// ---------------- K6: coef (redundant per block) + agg ----------------------
__global__ __launch_bounds__(256) void k_aggc(const float* __restrict__ E,
    const float* __restrict__ partial, float* __restrict__ agg)
{
  float S01 = 0, S02 = 0, S12 = 0;
  for (int b = 0; b < 16; ++b) {
    S01 += partial[b * 3 + 0];
    S02 += partial[b * 3 + 1];
    S12 += partial[b * 3 + 2];
  }
  S01 /= (float)NN; S02 /= (float)NN; S12 /= (float)NN;
  float mx = fmaxf(S01, fmaxf(S02, S12));
  float thr = 0.7f * mx;
  float w01 = (S01 > thr) ? S01 : 0.f;
  float w02 = (S02 > thr) ? S02 : 0.f;
  float m0 = fmaxf(w01, w02);
  float e01 = expf(w01 - m0), e02 = expf(w02 - m0);
  float s0 = e01 + e02;
  float p01 = e01 / s0, p02 = e02 / s0;
  float p12 = 1.0f;                      // row-1 softmax over its single edge
  float c0 = (p01 + p02) / 6.0f;
  float c1 = (p12 + p01) / 6.0f;
  float c2 = (p02 + p12) / 6.0f;
  int idx = blockIdx.x * 256 + threadIdx.x;
  agg[idx] = c0 * E[idx] + c1 * E[NN * CC + idx] + c2 * E[2 * NN * CC + idx];
}

// ---------------------------------------------------------------------------
extern "C" void kernel_launch(void* const* d_in, const int* in_sizes, int n_in,
                              void* d_out, int out_size, void* d_ws, size_t ws_size,
                              hipStream_t stream)
{
  (void)in_sizes; (void)n_in; (void)out_size;
  const float* X         = (const float*)d_in[0];
  const float* A         = (const float*)d_in[1];
  const float* consensus = (const float*)d_in[2];
  const float* W_mlp     = (const float*)d_in[3];
  const float* b_mlp     = (const float*)d_in[4];
  const float* W1        = (const float*)d_in[5];
  const float* b1        = (const float*)d_in[6];
  const float* W2        = (const float*)d_in[7];
  const float* b2        = (const float*)d_in[8];
  float* Eout = (float*)d_out;
  float* aggout = Eout + (size_t)VV * NN * CC;

  char* ws = (char*)d_ws;
  size_t off = 0;
  auto alloc = [&](size_t b) { char* p = ws + off; off += (b + 255) & ~(size_t)255; return p; };
  unsigned long long* mask = (unsigned long long*)alloc((size_t)VV * NN * 64 * 8);
  bf16_t* Wc_t  = (bf16_t*)alloc((size_t)VV * 16 * DD * 2);
  bf16_t* Wm_t  = (bf16_t*)alloc((size_t)VV * 16 * DD * 2);
  float*  bp    = (float*) alloc((size_t)VV * CC * 4);
  float*  dinv  = (float*) alloc((size_t)VV * NN * 4);
  unsigned* Ps1p = (unsigned*)alloc((size_t)VV * 5 * NN * 4);
  unsigned* P2p  = (unsigned*)alloc((size_t)VV * 5 * NN * 4);
  float*  partial = (float*)alloc(16 * 3 * 4);
  if (off > ws_size) return;

  k_prep <<<VV * NN / 4 + 385 + 6, 256, 0, stream>>>(A, W1, b1, W2, W_mlp,
                                                     mask, dinv, Wc_t, bp, Wm_t);
  k_zs   <<<dim3(NN / 64, VV), 256, 0, stream>>>(X, Wc_t, Wm_t, b_mlp, consensus,
                                                 dinv, Ps1p, Eout);
  k_spmm1<<<dim3(NN / 32, VV), 256, 0, stream>>>(mask, Ps1p, bp, dinv, P2p);
  k_spmm2<<<dim3(NN / 32, VV), 256, 0, stream>>>(mask, P2p, b2, dinv, Eout);
  k_sim  <<<NN / 256, 256, 0, stream>>>(Eout, partial);
  k_aggc <<<160, 256, 0, stream>>>(Eout, partial, aggout);
}